// Round 3
// baseline (763.296 us; speedup 1.0000x reference)
//
#include <hip/hip_runtime.h>

// CropSplitGT: out[h,w,i] = data[h,w,i] if (w,h) inside roi box i else 0.
// data layout (H, W, N), N innermost; rois layout (4, N) = [x1; y1; x2; y2].
// Memory-bound masked copy; floor = 419 MB write + ~340 MB line-granular read.
//
// Persistent-thread restructure exploiting divisibility:
//   total float4s = 512*512*100 = 26,214,400
//   T = total/16  = 1,638,400 threads, T % 100 == 0  -> each thread's i4 is FIXED
//     => rois (4 boxes) loaded ONCE per thread instead of per element (16x fewer),
//        div/mod-by-100 once per thread.
//   T/100 = 16,384 pixels = exactly 32 rows => across the 16 iterations,
//     w is CONSTANT (x-compares hoisted; all-miss-in-w threads take a pure
//     store-zeros fast path) and h advances by exactly 32 (hf += 32.0f).
// Coalescing is unchanged: consecutive threads touch consecutive float4s.
// Data load stays exec-masked: all-inactive 64B lines are never fetched.

constexpr int kH = 512;
constexpr int kW = 512;
constexpr int kN = 400;
constexpr int kN4 = kN / 4;                           // 100 float4 per pixel
constexpr long long kTotal4 = (long long)kH * kW * kN4;  // 26,214,400
constexpr int kLoop = 16;
constexpr int kThreads = (int)(kTotal4 / kLoop);      // 1,638,400 (% 100 == 0)
constexpr int kBlock = 256;
constexpr int kGrid = kThreads / kBlock;              // 6,400 blocks
constexpr int kStridePix = kThreads / kN4;            // 16,384 pixels = 32 rows
constexpr float kRowStep = (float)(kStridePix / kW);  // 32.0f exactly

static_assert(kTotal4 % kLoop == 0, "loop divides total");
static_assert(kThreads % kBlock == 0, "block divides threads");
static_assert(kThreads % kN4 == 0, "i4 fixed per thread");
static_assert(kStridePix % kW == 0, "w constant across iterations");

__global__ __launch_bounds__(kBlock) void crop_split_gt_kernel(
    const float4* __restrict__ data4,
    const float* __restrict__ rois,
    float4* __restrict__ out4)
{
    const int t0 = blockIdx.x * kBlock + threadIdx.x;   // exact grid, no tail

    const int i4     = t0 % kN4;         // fixed float4 index along N
    const int pixel0 = t0 / kN4;         // first pixel handled by this thread
    const int w  = pixel0 % kW;          // constant over all iterations
    const int h0 = pixel0 / kW;          // 0..31; h advances by 32/iter
    const float wf = (float)w;
    float hf = (float)h0;

    // rois rows are 400 floats (1600 B) apart -> 16B-aligned float4 loads,
    // one address + offset immediates. Loaded ONCE per thread.
    const int i = i4 * 4;
    const float4 x1 = *(const float4*)(rois + 0 * kN + i);
    const float4 y1 = *(const float4*)(rois + 1 * kN + i);
    const float4 x2 = *(const float4*)(rois + 2 * kN + i);
    const float4 y2 = *(const float4*)(rois + 3 * kN + i);

    // Hoisted x-axis membership (w constant for this thread).
    const bool mw0 = (wf >= x1.x) & (wf <= x2.x);
    const bool mw1 = (wf >= x1.y) & (wf <= x2.y);
    const bool mw2 = (wf >= x1.z) & (wf <= x2.z);
    const bool mw3 = (wf >= x1.w) & (wf <= x2.w);

    const float4* __restrict__ pin  = data4 + t0;
    float4* __restrict__       pout = out4 + t0;

    if (!(mw0 | mw1 | mw2 | mw3)) {
        // All 4 ROIs miss this w for every h: pure streaming zero-store.
        const float4 z = {0.f, 0.f, 0.f, 0.f};
#pragma unroll
        for (int j = 0; j < kLoop; ++j) {
            *pout = z;
            pout += kThreads;
        }
        return;
    }

#pragma unroll
    for (int j = 0; j < kLoop; ++j) {
        const bool m0 = mw0 & (hf >= y1.x) & (hf <= y2.x);
        const bool m1 = mw1 & (hf >= y1.y) & (hf <= y2.y);
        const bool m2 = mw2 & (hf >= y1.z) & (hf <= y2.z);
        const bool m3 = mw3 & (hf >= y1.w) & (hf <= y2.w);

        float4 o = {0.f, 0.f, 0.f, 0.f};
        if (m0 | m1 | m2 | m3) {
            const float4 d = *pin;   // exec-masked: all-inactive lines not fetched
            if (m0) o.x = d.x;
            if (m1) o.y = d.y;
            if (m2) o.z = d.z;
            if (m3) o.w = d.w;
        }
        *pout = o;

        pin  += kThreads;
        pout += kThreads;
        hf   += kRowStep;            // h advances by exactly 32 rows
    }
}

extern "C" void kernel_launch(void* const* d_in, const int* in_sizes, int n_in,
                              void* d_out, int out_size, void* d_ws, size_t ws_size,
                              hipStream_t stream) {
    const float4* data4 = (const float4*)d_in[0];
    const float*  rois  = (const float*)d_in[1];
    // d_in[2] = c (unused by the GT variant)
    float4* out4 = (float4*)d_out;

    crop_split_gt_kernel<<<kGrid, kBlock, 0, stream>>>(data4, rois, out4);
}

// Round 4
// 645.295 us; speedup vs baseline: 1.1829x; 1.1829x over previous
//
#include <hip/hip_runtime.h>

// CropSplitGT: out[h,w,i] = data[h,w,i] if (w,h) inside roi box i else 0.
// data layout (H, W, N), N innermost; rois layout (4, N) = [x1; y1; x2; y2].
// Memory-bound masked copy; floor = 419 MB write + ~340 MB line-granular read.
//
// Persistent-thread structure exploiting divisibility:
//   total float4s = 512*512*100 = 26,214,400
//   T = total/16  = 1,638,400 threads; T % 100 == 0 -> each thread's i4 is FIXED
//     => rois (4 boxes) loaded ONCE per thread (was 4 VMEM issues per element),
//        div/mod-by-100 once per thread.
//   T/100 = 16,384 pixels = exactly 32 rows => across the 16 iterations,
//     w is CONSTANT (x-compares hoisted out of the loop) and h advances by
//     exactly 32 (hf += 32.0f). Per element: 4 y-cmps + masked load + store.
//
// Round-3 post-mortem: the "all-miss-in-w" per-thread fast path REGRESSED
// (~+40 us). Divergence is per-wave: essentially every wave was mixed, so both
// the fast path and the main loop executed under complementary exec masks ->
// 2x store issues per wave. Fast path removed; single main loop only.
//
// Coalescing unchanged: consecutive threads touch consecutive float4s.
// Data load stays exec-masked: all-inactive 64B lines are never fetched;
// the if() adds a free whole-wave execz skip.

constexpr int kH = 512;
constexpr int kW = 512;
constexpr int kN = 400;
constexpr int kN4 = kN / 4;                           // 100 float4 per pixel
constexpr long long kTotal4 = (long long)kH * kW * kN4;  // 26,214,400
constexpr int kLoop = 16;
constexpr int kThreads = (int)(kTotal4 / kLoop);      // 1,638,400 (% 100 == 0)
constexpr int kBlock = 256;
constexpr int kGrid = kThreads / kBlock;              // 6,400 blocks
constexpr int kStridePix = kThreads / kN4;            // 16,384 pixels = 32 rows
constexpr float kRowStep = (float)(kStridePix / kW);  // 32.0f exactly

static_assert(kTotal4 % kLoop == 0, "loop divides total");
static_assert(kThreads % kBlock == 0, "block divides threads");
static_assert(kThreads % kN4 == 0, "i4 fixed per thread");
static_assert(kStridePix % kW == 0, "w constant across iterations");

__global__ __launch_bounds__(kBlock) void crop_split_gt_kernel(
    const float4* __restrict__ data4,
    const float* __restrict__ rois,
    float4* __restrict__ out4)
{
    const int t0 = blockIdx.x * kBlock + threadIdx.x;   // exact grid, no tail

    const int i4     = t0 % kN4;         // fixed float4 index along N
    const int pixel0 = t0 / kN4;         // first pixel handled by this thread
    const int w  = pixel0 % kW;          // constant over all iterations
    const int h0 = pixel0 / kW;          // 0..31; h advances by 32/iter
    const float wf = (float)w;
    float hf = (float)h0;

    // rois rows are 400 floats (1600 B) apart -> 16B-aligned float4 loads,
    // loaded ONCE per thread (L1-broadcast across the 100 threads per pixel).
    const int i = i4 * 4;
    const float4 x1 = *(const float4*)(rois + 0 * kN + i);
    const float4 y1 = *(const float4*)(rois + 1 * kN + i);
    const float4 x2 = *(const float4*)(rois + 2 * kN + i);
    const float4 y2 = *(const float4*)(rois + 3 * kN + i);

    // Hoisted x-axis membership (w constant for this thread).
    const bool mw0 = (wf >= x1.x) & (wf <= x2.x);
    const bool mw1 = (wf >= x1.y) & (wf <= x2.y);
    const bool mw2 = (wf >= x1.z) & (wf <= x2.z);
    const bool mw3 = (wf >= x1.w) & (wf <= x2.w);

    const float4* __restrict__ pin  = data4 + t0;
    float4* __restrict__       pout = out4 + t0;

#pragma unroll
    for (int j = 0; j < kLoop; ++j) {
        const bool m0 = mw0 & (hf >= y1.x) & (hf <= y2.x);
        const bool m1 = mw1 & (hf >= y1.y) & (hf <= y2.y);
        const bool m2 = mw2 & (hf >= y1.z) & (hf <= y2.z);
        const bool m3 = mw3 & (hf >= y1.w) & (hf <= y2.w);

        float4 o = {0.f, 0.f, 0.f, 0.f};
        if (m0 | m1 | m2 | m3) {
            const float4 d = *pin;   // exec-masked: all-inactive lines not fetched
            if (m0) o.x = d.x;
            if (m1) o.y = d.y;
            if (m2) o.z = d.z;
            if (m3) o.w = d.w;
        }
        *pout = o;                   // exactly ONE store issue per element

        pin  += kThreads;
        pout += kThreads;
        hf   += kRowStep;            // h advances by exactly 32 rows
    }
}

extern "C" void kernel_launch(void* const* d_in, const int* in_sizes, int n_in,
                              void* d_out, int out_size, void* d_ws, size_t ws_size,
                              hipStream_t stream) {
    const float4* data4 = (const float4*)d_in[0];
    const float*  rois  = (const float*)d_in[1];
    // d_in[2] = c (unused by the GT variant)
    float4* out4 = (float4*)d_out;

    crop_split_gt_kernel<<<kGrid, kBlock, 0, stream>>>(data4, rois, out4);
}

// Round 6
// 632.591 us; speedup vs baseline: 1.2066x; 1.0201x over previous
//
#include <hip/hip_runtime.h>

// CropSplitGT: out[h,w,i] = data[h,w,i] if (w,h) inside roi box i else 0.
// data layout (H, W, N), N innermost; rois layout (4, N) = [x1; y1; x2; y2].
// Memory-bound masked copy; floor = 419 MB write + ~340 MB line-granular read
// = 760 MB @ ~6.3 TB/s ~= 121 us kernel slice.
//
// Persistent-thread structure (proven -49 us in R4 vs baseline):
//   total float4s = 512*512*100 = 26,214,400
//   T = total/16 = 1,638,400 threads; T % 100 == 0 -> each thread's i4 FIXED
//     => rois loaded ONCE per thread; div/mod-by-100 once per thread.
//   T/100 = 16,384 pixels = exactly 32 rows => w CONSTANT per thread
//     (x-compares hoisted), h advances by exactly 32 per iteration.
//   Single main loop, ONE store issue per element (R3's divergent fast path
//   regressed ~+40 us: every wave was mixed -> both paths executed).
//
// R6 = R5 with the compile fix: __builtin_nontemporal_* requires native
// clang vector types, not HIP_vector_type. nt accesses go through
// ext_vector_type(4) pointers (bit-identical layout). out (419 MB) and
// data (419 MB) are pure streams with zero reuse >> 32 MB L2; nt bypasses
// L2 allocation so the write stream stops thrashing the read stream.
// Rois (1.6 KB, reused by all waves) stay cached.
// Discriminator: at-floor -> no-op (then ROOFLINE); L2-thrash -> -20..-40 us.

typedef float f32x4 __attribute__((ext_vector_type(4)));

constexpr int kH = 512;
constexpr int kW = 512;
constexpr int kN = 400;
constexpr int kN4 = kN / 4;                           // 100 float4 per pixel
constexpr long long kTotal4 = (long long)kH * kW * kN4;  // 26,214,400
constexpr int kLoop = 16;
constexpr int kThreads = (int)(kTotal4 / kLoop);      // 1,638,400 (% 100 == 0)
constexpr int kBlock = 256;
constexpr int kGrid = kThreads / kBlock;              // 6,400 blocks
constexpr int kStridePix = kThreads / kN4;            // 16,384 pixels = 32 rows
constexpr float kRowStep = (float)(kStridePix / kW);  // 32.0f exactly

static_assert(kTotal4 % kLoop == 0, "loop divides total");
static_assert(kThreads % kBlock == 0, "block divides threads");
static_assert(kThreads % kN4 == 0, "i4 fixed per thread");
static_assert(kStridePix % kW == 0, "w constant across iterations");
static_assert(sizeof(f32x4) == sizeof(float4), "layout match");

__global__ __launch_bounds__(kBlock) void crop_split_gt_kernel(
    const f32x4* __restrict__ data4,
    const float* __restrict__ rois,
    f32x4* __restrict__ out4)
{
    const int t0 = blockIdx.x * kBlock + threadIdx.x;   // exact grid, no tail

    const int i4     = t0 % kN4;         // fixed float4 index along N
    const int pixel0 = t0 / kN4;         // first pixel handled by this thread
    const int w  = pixel0 % kW;          // constant over all iterations
    const int h0 = pixel0 / kW;          // 0..31; h advances by 32/iter
    const float wf = (float)w;
    float hf = (float)h0;

    // rois rows are 400 floats (1600 B) apart -> 16B-aligned float4 loads,
    // loaded ONCE per thread; cached path (1.6 KB, reused by every wave).
    const int i = i4 * 4;
    const float4 x1 = *(const float4*)(rois + 0 * kN + i);
    const float4 y1 = *(const float4*)(rois + 1 * kN + i);
    const float4 x2 = *(const float4*)(rois + 2 * kN + i);
    const float4 y2 = *(const float4*)(rois + 3 * kN + i);

    // Hoisted x-axis membership (w constant for this thread).
    const bool mw0 = (wf >= x1.x) & (wf <= x2.x);
    const bool mw1 = (wf >= x1.y) & (wf <= x2.y);
    const bool mw2 = (wf >= x1.z) & (wf <= x2.z);
    const bool mw3 = (wf >= x1.w) & (wf <= x2.w);

    const f32x4* __restrict__ pin  = data4 + t0;
    f32x4* __restrict__       pout = out4 + t0;

#pragma unroll
    for (int j = 0; j < kLoop; ++j) {
        const bool m0 = mw0 & (hf >= y1.x) & (hf <= y2.x);
        const bool m1 = mw1 & (hf >= y1.y) & (hf <= y2.y);
        const bool m2 = mw2 & (hf >= y1.z) & (hf <= y2.z);
        const bool m3 = mw3 & (hf >= y1.w) & (hf <= y2.w);

        f32x4 o = {0.f, 0.f, 0.f, 0.f};
        if (m0 | m1 | m2 | m3) {
            // exec-masked: all-inactive 64B lines never fetched; nt -> no L2 alloc
            const f32x4 d = __builtin_nontemporal_load(pin);
            if (m0) o.x = d.x;
            if (m1) o.y = d.y;
            if (m2) o.z = d.z;
            if (m3) o.w = d.w;
        }
        __builtin_nontemporal_store(o, pout);   // one store issue/element, L2-bypass

        pin  += kThreads;
        pout += kThreads;
        hf   += kRowStep;            // h advances by exactly 32 rows
    }
}

extern "C" void kernel_launch(void* const* d_in, const int* in_sizes, int n_in,
                              void* d_out, int out_size, void* d_ws, size_t ws_size,
                              hipStream_t stream) {
    const f32x4* data4 = (const f32x4*)d_in[0];
    const float* rois  = (const float*)d_in[1];
    // d_in[2] = c (unused by the GT variant)
    f32x4* out4 = (f32x4*)d_out;

    crop_split_gt_kernel<<<kGrid, kBlock, 0, stream>>>(data4, rois, out4);
}